// Round 1
// baseline (38262.744 us; speedup 1.0000x reference)
//
#include <hip/hip_runtime.h>

// CharRNN: 3-layer shared-weight LSTM (H=65) over T=4096, B=50, + dense head.
// One persistent workgroup per sequence. Layers wavefront-pipelined:
//   round r: layer l computes timestep t = r - l  (l = 0,1,2), dense does t = r-3.
// Gate threads hold their W/U columns in registers (260 VGPRs), state lives in LDS.

#define HH     65
#define G4     260      // 4*H
#define TT     4096
#define NB     50
#define NPAIR  130      // gate pairs per layer (thread j does gates j and j+130)
#define NGT    390      // 3 layers * 130 pair-threads
#define NCELL  195      // 3 layers * 65 cells
#define BLOCK  448      // 390 gate threads + 58 aux (x-prefetch + dense head)

__device__ __forceinline__ float sigm(float x)  { return 1.0f / (1.0f + __expf(-x)); }
__device__ __forceinline__ float tanha(float x) { float e = __expf(2.0f * x); return 1.0f - 2.0f / (e + 1.0f); }

__global__ void __launch_bounds__(BLOCK, 1)
charrnn_fused(const float* __restrict__ x,  const float* __restrict__ W,
              const float* __restrict__ U,  const float* __restrict__ bv,
              const float* __restrict__ Wd, const float* __restrict__ bd,
              float* __restrict__ out)
{
    __shared__ __align__(16) float s_hin[3][68];   // input to each layer this round (row 0 = x(t))
    __shared__ __align__(16) float s_hrec[3][68];  // recurrent h state per layer
    __shared__ float s_crec[3][HH];                // cell state per layer
    __shared__ float s_z[3][G4];                   // gate pre-activations

    const int bat = blockIdx.x;
    const int tid = threadIdx.x;
    const float* xb   = x   + (size_t)bat * TT * HH;
    float*       outb = out + (size_t)bat * TT * HH;

    // zero-init LDS state
    for (int i = tid; i < 3 * 68; i += BLOCK) { (&s_hin[0][0])[i] = 0.0f; (&s_hrec[0][0])[i] = 0.0f; }
    for (int i = tid; i < 3 * HH; i += BLOCK) (&s_crec[0][0])[i] = 0.0f;

    // role-dependent register weight storage (unioned: gates use all 4 arrays,
    // aux/dense threads use wg0/wg1 for Wd columns)
    float wg0[HH], wg1[HH], wg2[HH], wg3[HH];
    float rb0 = 0.0f, rb1 = 0.0f;
    int l = 0, p = 0, q = 0, m1 = -1;

    if (tid < NGT) {
        l = tid / NPAIR; p = tid - l * NPAIR;
        const int jA = p, jB = p + NPAIR;
#pragma unroll
        for (int k = 0; k < HH; ++k) {
            wg0[k] = W[k * G4 + jA];
            wg1[k] = W[k * G4 + jB];
            wg2[k] = U[k * G4 + jA];
            wg3[k] = U[k * G4 + jB];
        }
        rb0 = bv[jA]; rb1 = bv[jB];
    } else {
        q = tid - NGT;                       // 0..57
        m1 = (q + 58 < HH) ? (q + 58) : -1;  // q<7 handle a second output column
#pragma unroll
        for (int k = 0; k < HH; ++k) {
            wg0[k] = Wd[k * HH + q];
            wg1[k] = (m1 >= 0) ? Wd[k * HH + m1] : 0.0f;
            wg2[k] = 0.0f; wg3[k] = 0.0f;
        }
        rb0 = bd[q]; rb1 = (m1 >= 0) ? bd[m1] : 0.0f;
    }

    // x prefetch (depth 2, in registers): x(0) -> LDS now, x(1) -> cur
    float cur0 = 0.0f, cur1 = 0.0f, nxt0 = 0.0f, nxt1 = 0.0f;
    if (tid >= NGT) {
        s_hin[0][q] = xb[q];
        if (m1 >= 0) s_hin[0][m1] = xb[m1];
        cur0 = xb[HH + q];
        if (m1 >= 0) cur1 = xb[HH + m1];
    }
    __syncthreads();

    for (int r = 0; r < TT + 3; ++r) {
        // ---------- Phase A ----------
        if (tid < NGT) {
            const float* hi = &s_hin[l][0];
            const float* hr = &s_hrec[l][0];
            float a0 = rb0, a1 = rb1, c0 = 0.0f, c1 = 0.0f;
#pragma unroll
            for (int k = 0; k < 64; k += 4) {
                const float4 hv = *(const float4*)(hi + k);
                const float4 rv = *(const float4*)(hr + k);
                a0 = fmaf(hv.x, wg0[k+0], a0); a1 = fmaf(hv.x, wg1[k+0], a1);
                c0 = fmaf(rv.x, wg2[k+0], c0); c1 = fmaf(rv.x, wg3[k+0], c1);
                a0 = fmaf(hv.y, wg0[k+1], a0); a1 = fmaf(hv.y, wg1[k+1], a1);
                c0 = fmaf(rv.y, wg2[k+1], c0); c1 = fmaf(rv.y, wg3[k+1], c1);
                a0 = fmaf(hv.z, wg0[k+2], a0); a1 = fmaf(hv.z, wg1[k+2], a1);
                c0 = fmaf(rv.z, wg2[k+2], c0); c1 = fmaf(rv.z, wg3[k+2], c1);
                a0 = fmaf(hv.w, wg0[k+3], a0); a1 = fmaf(hv.w, wg1[k+3], a1);
                c0 = fmaf(rv.w, wg2[k+3], c0); c1 = fmaf(rv.w, wg3[k+3], c1);
            }
            {
                const float hv = hi[64], rv = hr[64];
                a0 = fmaf(hv, wg0[64], a0); a1 = fmaf(hv, wg1[64], a1);
                c0 = fmaf(rv, wg2[64], c0); c1 = fmaf(rv, wg3[64], c1);
            }
            s_z[l][p]         = a0 + c0;
            s_z[l][p + NPAIR] = a1 + c1;
        } else {
            // issue x(r+2) prefetch (latency hidden under gate FMAs)
            const int tn = r + 2;
            if (tn < TT) {
                nxt0 = xb[(size_t)tn * HH + q];
                nxt1 = (m1 >= 0) ? xb[(size_t)tn * HH + m1] : 0.0f;
            } else { nxt0 = 0.0f; nxt1 = 0.0f; }
            // dense head on h2 produced last round (t = r-3)
            const int td = r - 3;
            if (td >= 0) {
                const float* h2 = &s_hrec[2][0];
                float y0 = rb0, y1 = rb1;
#pragma unroll
                for (int k = 0; k < HH; ++k) {
                    y0 = fmaf(h2[k], wg0[k], y0);
                    y1 = fmaf(h2[k], wg1[k], y1);
                }
                outb[(size_t)td * HH + q] = y0;
                if (m1 >= 0) outb[(size_t)td * HH + m1] = y1;
            }
        }
        __syncthreads();

        // ---------- Phase B ----------
        if (tid < NCELL) {
            const int cl = tid / HH, n = tid - cl * HH;
            const int t = r - cl;
            if (t >= 0 && t < TT) {
                const float zi = s_z[cl][n];
                const float zf = s_z[cl][HH + n];
                const float zg = s_z[cl][2 * HH + n];
                const float zo = s_z[cl][3 * HH + n];
                const float ig = sigm(zi), fg = sigm(zf), gg = tanha(zg), og = sigm(zo);
                const float c = fmaf(fg, s_crec[cl][n], ig * gg);
                const float h = og * tanha(c);
                s_crec[cl][n] = c;
                s_hrec[cl][n] = h;
                if (cl < 2) s_hin[cl + 1][n] = h;   // feed next layer next round
            }
        }
        if (tid >= NGT) {
            const int tn = r + 1;
            if (tn < TT) { s_hin[0][q] = cur0; if (m1 >= 0) s_hin[0][m1] = cur1; }
            cur0 = nxt0; cur1 = nxt1;
        }
        __syncthreads();
    }
}

extern "C" void kernel_launch(void* const* d_in, const int* in_sizes, int n_in,
                              void* d_out, int out_size, void* d_ws, size_t ws_size,
                              hipStream_t stream)
{
    const float* x  = (const float*)d_in[0];
    const float* W  = (const float*)d_in[1];
    const float* U  = (const float*)d_in[2];
    const float* bv = (const float*)d_in[3];
    const float* Wd = (const float*)d_in[4];
    const float* bd = (const float*)d_in[5];
    float* out = (float*)d_out;

    hipLaunchKernelGGL(charrnn_fused, dim3(NB), dim3(BLOCK), 0, stream,
                       x, W, U, bv, Wd, bd, out);
}

// Round 2
// 28787.402 us; speedup vs baseline: 1.3291x; 1.3291x over previous
//
#include <hip/hip_runtime.h>

// CharRNN: 3-layer shared-weight LSTM (H=65) over T=4096, B=50, + dense head.
// One persistent workgroup per sequence. Layers wavefront-pipelined:
//   round r: layer l computes timestep t = r - l (l = 0,1,2); dense head does t = r-3.
//
// Round-2 change vs round-1: ONE gate column per thread (was two). 130 register
// weights/thread instead of 260 — round 1 exceeded the 256 addressable-VGPR
// arch limit and spilled to scratch (VGPR_Count=128, 22.5K cyc/round latency-bound).

#define HH     65
#define G4     260      // 4*H
#define TT     4096
#define NB     50
#define NGATE  780      // 3 layers * 260 gate columns, one thread each
#define NCELL  195      // 3 layers * 65 cells
#define BLOCK  896      // 780 gate + 116 aux (65 active: dense col + x prefetch)

__device__ __forceinline__ float sigm(float x)  { return 1.0f / (1.0f + __expf(-x)); }
__device__ __forceinline__ float tanha(float x) { float e = __expf(2.0f * x); return 1.0f - 2.0f / (e + 1.0f); }

__global__ void __launch_bounds__(BLOCK, 1)
charrnn_fused(const float* __restrict__ x,  const float* __restrict__ W,
              const float* __restrict__ U,  const float* __restrict__ bv,
              const float* __restrict__ Wd, const float* __restrict__ bd,
              float* __restrict__ out)
{
    __shared__ __align__(16) float s_hin[3][68];   // input to each layer this round (row 0 = x(t))
    __shared__ __align__(16) float s_hrec[3][68];  // recurrent h state per layer
    __shared__ float s_crec[3][HH];                // cell state per layer
    __shared__ float s_z[3][G4];                   // gate pre-activations

    const int bat = blockIdx.x;
    const int tid = threadIdx.x;
    const float* xb   = x   + (size_t)bat * TT * HH;
    float*       outb = out + (size_t)bat * TT * HH;

    // zero-init LDS state
    for (int i = tid; i < 3 * 68; i += BLOCK) { (&s_hin[0][0])[i] = 0.0f; (&s_hrec[0][0])[i] = 0.0f; }
    for (int i = tid; i < 3 * HH; i += BLOCK) (&s_crec[0][0])[i] = 0.0f;

    // 130 register-resident weights per thread (gate: W col + U col; aux: Wd col in wx)
    float wx[HH], wh[HH];
    float bias = 0.0f;
    int l = 0, j = 0, q = -1;

    if (tid < NGATE) {
        l = tid / G4; j = tid - l * G4;
#pragma unroll
        for (int k = 0; k < HH; ++k) {
            wx[k] = W[k * G4 + j];
            wh[k] = U[k * G4 + j];
        }
        bias = bv[j];
    } else {
        q = tid - NGATE;                 // 0..115; only q<65 active
        if (q < HH) {
#pragma unroll
            for (int k = 0; k < HH; ++k) { wx[k] = Wd[k * HH + q]; wh[k] = 0.0f; }
            bias = bd[q];
        } else {
#pragma unroll
            for (int k = 0; k < HH; ++k) { wx[k] = 0.0f; wh[k] = 0.0f; }
        }
    }

    // x prefetch (depth 2, in registers): x(0) -> LDS now, x(1) -> cur
    float cur = 0.0f, nxt = 0.0f;
    if (q >= 0 && q < HH) {
        s_hin[0][q] = xb[q];
        cur = xb[HH + q];
    }
    __syncthreads();

    for (int r = 0; r < TT + 3; ++r) {
        // ---------- Phase A ----------
        if (tid < NGATE) {
            const float* hi = &s_hin[l][0];
            const float* hr = &s_hrec[l][0];
            float a = bias, c = 0.0f;
#pragma unroll
            for (int k = 0; k < 64; k += 4) {
                const float4 hv = *(const float4*)(hi + k);
                const float4 rv = *(const float4*)(hr + k);
                a = fmaf(hv.x, wx[k+0], a);  c = fmaf(rv.x, wh[k+0], c);
                a = fmaf(hv.y, wx[k+1], a);  c = fmaf(rv.y, wh[k+1], c);
                a = fmaf(hv.z, wx[k+2], a);  c = fmaf(rv.z, wh[k+2], c);
                a = fmaf(hv.w, wx[k+3], a);  c = fmaf(rv.w, wh[k+3], c);
            }
            a = fmaf(hi[64], wx[64], a);
            c = fmaf(hr[64], wh[64], c);
            s_z[l][j] = a + c;
        } else if (q < HH) {
            // issue x(r+2) prefetch (latency hidden under gate FMAs)
            const int tn = r + 2;
            nxt = (tn < TT) ? xb[(size_t)tn * HH + q] : 0.0f;
            // dense head on h2 produced last round (t = r-3)
            const int td = r - 3;
            if (td >= 0) {
                const float* h2 = &s_hrec[2][0];
                float y = bias;
#pragma unroll
                for (int k = 0; k < 64; k += 4) {
                    const float4 hv = *(const float4*)(h2 + k);
                    y = fmaf(hv.x, wx[k+0], y);
                    y = fmaf(hv.y, wx[k+1], y);
                    y = fmaf(hv.z, wx[k+2], y);
                    y = fmaf(hv.w, wx[k+3], y);
                }
                y = fmaf(h2[64], wx[64], y);
                outb[(size_t)td * HH + q] = y;
            }
        }
        __syncthreads();

        // ---------- Phase B ----------
        if (tid < NCELL) {
            const int cl = tid / HH, n = tid - cl * HH;
            const int t = r - cl;
            if (t >= 0 && t < TT) {
                const float zi = s_z[cl][n];
                const float zf = s_z[cl][HH + n];
                const float zg = s_z[cl][2 * HH + n];
                const float zo = s_z[cl][3 * HH + n];
                const float ig = sigm(zi), fg = sigm(zf), gg = tanha(zg), og = sigm(zo);
                const float c = fmaf(fg, s_crec[cl][n], ig * gg);
                const float h = og * tanha(c);
                s_crec[cl][n] = c;
                s_hrec[cl][n] = h;
                if (cl < 2) s_hin[cl + 1][n] = h;   // feed next layer next round
            }
        }
        if (q >= 0 && q < HH) {
            const int tn = r + 1;
            if (tn < TT) s_hin[0][q] = cur;
            cur = nxt;
        }
        __syncthreads();
    }
}

extern "C" void kernel_launch(void* const* d_in, const int* in_sizes, int n_in,
                              void* d_out, int out_size, void* d_ws, size_t ws_size,
                              hipStream_t stream)
{
    const float* x  = (const float*)d_in[0];
    const float* W  = (const float*)d_in[1];
    const float* U  = (const float*)d_in[2];
    const float* bv = (const float*)d_in[3];
    const float* Wd = (const float*)d_in[4];
    const float* bd = (const float*)d_in[5];
    float* out = (float*)d_out;

    hipLaunchKernelGGL(charrnn_fused, dim3(NB), dim3(BLOCK), 0, stream,
                       x, W, U, bv, Wd, bd, out);
}

// Round 3
// 13925.766 us; speedup vs baseline: 2.7476x; 2.0672x over previous
//
#include <hip/hip_runtime.h>

// CharRNN: 3-layer shared-weight LSTM (H=65) over T=4096, B=50, + dense head.
//
// Kernel 1 (recurrent): one workgroup per sequence, layers wavefront-pipelined
//   (round r: layer l does t=r-l). Weight-sharing exploited: thread owns ONE
//   W-column or ONE U-column (65 floats in VGPRs) and computes it for ALL 3
//   layers. Block=512 (8 waves, 2/SIMD -> 256-VGPR cap; need ~90: no spill).
//   Top-layer h is streamed to d_out.
// Kernel 2 (dense head): in-place y = h2 @ Wd + bd over d_out, 64 rows/block.

#define HH    65
#define G4    260
#define TT    4096
#define NB    50
#define BLOCK 512
#define DROWS 64

__device__ __forceinline__ float sigm(float x)  { return 1.0f / (1.0f + __expf(-x)); }
__device__ __forceinline__ float tanha(float x) { float e = __expf(2.0f * x); return 1.0f - 2.0f / (e + 1.0f); }

__global__ void __launch_bounds__(BLOCK, 1)
charrnn_rec(const float* __restrict__ x, const float* __restrict__ W,
            const float* __restrict__ U, const float* __restrict__ bv,
            float* __restrict__ out)
{
    __shared__ __align__(16) float s_hin[3][68];   // input to layer l this round (row0 = x(t))
    __shared__ __align__(16) float s_hrec[3][68];  // recurrent h per layer
    __shared__ float s_crec[3][HH];
    __shared__ float s_zW[3][G4];                  // x/hin-side partial pre-activations
    __shared__ float s_zU[3][G4];                  // hrec-side partials (cols 0..251)
    __shared__ float s_zUe[3][8][8];               // hrec-side partials, cols 252..259, 8 k-chunks

    const int bat  = blockIdx.x;
    const int tid  = threadIdx.x;
    const int lane = tid & 63;
    const int wv   = tid >> 6;
    const float* xb   = x   + (size_t)bat * TT * HH;
    float*       outb = out + (size_t)bat * TT * HH;

    for (int i = tid; i < 3 * 68; i += BLOCK) { (&s_hin[0][0])[i] = 0.0f; (&s_hrec[0][0])[i] = 0.0f; }
    for (int i = tid; i < 3 * HH; i += BLOCK) (&s_crec[0][0])[i] = 0.0f;

    // ---- main slot: W-column (tid<260) or U-column (tid-260 in [0,252)) ----
    const bool isW = (tid < G4);
    const int  col = isW ? tid : tid - G4;
    float wgt[HH];
    float bias = 0.0f;
    if (isW) {
#pragma unroll
        for (int k = 0; k < HH; ++k) wgt[k] = W[k * G4 + col];
        bias = bv[col];
    } else {
#pragma unroll
        for (int k = 0; k < HH; ++k) wgt[k] = U[k * G4 + col];
    }

    // ---- leftover U-columns 252..259: k-chunk wv on lanes 56..63 of each wave ----
    const bool isL  = (lane >= 56);
    const int  lc   = lane - 56;                       // 0..7 -> col 252+lc
    const int  kst  = (wv == 0) ? 0 : (9 + 8 * (wv - 1));
    const int  kln  = (wv == 0) ? 9 : 8;
    float ew[9];
#pragma unroll
    for (int i = 0; i < 9; ++i) ew[i] = 0.0f;
    if (isL) {
#pragma unroll
        for (int i = 0; i < 9; ++i) if (i < kln) ew[i] = U[(kst + i) * G4 + (252 + lc)];
    }

    // ---- x prefetch role: 65 lanes (lanes 40..47 of each wave + tid 48) ----
    const bool isP  = (lane >= 40 && lane < 48) || (tid == 48);
    const int  pidx = (tid == 48) ? 64 : (wv * 8 + (lane - 40));
    float cur = 0.0f, nxt = 0.0f;
    if (isP) {
        s_hin[0][pidx] = xb[pidx];       // x(0)
        cur = xb[HH + pidx];             // x(1)
    }
    __syncthreads();

    for (int r = 0; r < TT + 2; ++r) {
        // ---------------- Phase A: gate partial dot-products ----------------
#pragma unroll
        for (int l = 0; l < 3; ++l) {
            if ((unsigned)(r - l) < TT) {
                const float* s = isW ? &s_hin[l][0] : &s_hrec[l][0];
                float a = isW ? bias : 0.0f;
#pragma unroll
                for (int k = 0; k < 64; k += 4) {
                    const float4 hv = *(const float4*)(s + k);
                    a = fmaf(hv.x, wgt[k + 0], a);
                    a = fmaf(hv.y, wgt[k + 1], a);
                    a = fmaf(hv.z, wgt[k + 2], a);
                    a = fmaf(hv.w, wgt[k + 3], a);
                }
                a = fmaf(s[64], wgt[64], a);
                if (isW) s_zW[l][col] = a; else s_zU[l][col] = a;
            }
        }
        if (isL) {
#pragma unroll
            for (int l = 0; l < 3; ++l) {
                if ((unsigned)(r - l) < TT) {
                    float a = 0.0f;
#pragma unroll
                    for (int i = 0; i < 9; ++i) a = fmaf(s_hrec[l][kst + i], ew[i], a);
                    s_zUe[l][wv][lc] = a;
                }
            }
        }
        if (isP) {  // issue x(r+2); latency hidden under gate FMAs
            const int tn = r + 2;
            nxt = (tn < TT) ? xb[(size_t)tn * HH + pidx] : 0.0f;
        }
        __syncthreads();

        // ---------------- Phase B: cell updates ----------------
        if (tid < 195) {
            const int cl = tid / 65, n = tid - cl * 65;
            const int t  = r - cl;
            if ((unsigned)t < TT) {
                const float zi = s_zW[cl][n]        + s_zU[cl][n];
                const float zf = s_zW[cl][65 + n]   + s_zU[cl][65 + n];
                const float zg = s_zW[cl][130 + n]  + s_zU[cl][130 + n];
                float zo = s_zW[cl][195 + n];
                if (n < 57) {
                    zo += s_zU[cl][195 + n];
                } else {
                    float a = 0.0f;
#pragma unroll
                    for (int w8 = 0; w8 < 8; ++w8) a += s_zUe[cl][w8][n - 57];
                    zo += a;
                }
                const float ig = sigm(zi), fg = sigm(zf), gg = tanha(zg), og = sigm(zo);
                const float c = fmaf(fg, s_crec[cl][n], ig * gg);
                const float h = og * tanha(c);
                s_crec[cl][n] = c;
                s_hrec[cl][n] = h;
                if (cl < 2) s_hin[cl + 1][n] = h;
                else        outb[(size_t)t * HH + n] = h;   // stream h2 to out
            }
        }
        if (isP) {
            if (r + 1 < TT) s_hin[0][pidx] = cur;
            cur = nxt;
        }
        __syncthreads();
    }
}

// ---- kernel 2: in-place dense head over d_out: y = h2 @ Wd + bd ----
__global__ void __launch_bounds__(256, 1)
dense_head(float* __restrict__ io, const float* __restrict__ Wd, const float* __restrict__ bd)
{
    __shared__ __align__(16) float s_h[DROWS][68];  // 64 rows of h2, padded for float4
    __shared__ float s_wd[HH][HH];                  // Wd as-is: [k][c]
    __shared__ float s_bd[HH];

    const int tid = threadIdx.x;
    float* base = io + (size_t)blockIdx.x * DROWS * HH;

    for (int i = tid; i < DROWS * HH; i += 256) {
        const int row = i / HH, k = i - row * HH;
        s_h[row][k] = base[i];
    }
    for (int i = tid; i < HH * HH; i += 256) (&s_wd[0][0])[i] = Wd[i];
    if (tid < HH) s_bd[tid] = bd[tid];
    __syncthreads();

    for (int u = tid; u < DROWS * HH; u += 256) {
        const int row = u / HH, c = u - row * HH;
        const float4* hp = (const float4*)&s_h[row][0];
        float acc = s_bd[c];
#pragma unroll
        for (int k4 = 0; k4 < 16; ++k4) {
            const float4 hv = hp[k4];
            acc = fmaf(hv.x, s_wd[4 * k4 + 0][c], acc);
            acc = fmaf(hv.y, s_wd[4 * k4 + 1][c], acc);
            acc = fmaf(hv.z, s_wd[4 * k4 + 2][c], acc);
            acc = fmaf(hv.w, s_wd[4 * k4 + 3][c], acc);
        }
        acc = fmaf(s_h[row][64], s_wd[64][c], acc);
        base[u] = acc;   // safe: all reads come from LDS copies
    }
}

extern "C" void kernel_launch(void* const* d_in, const int* in_sizes, int n_in,
                              void* d_out, int out_size, void* d_ws, size_t ws_size,
                              hipStream_t stream)
{
    const float* x  = (const float*)d_in[0];
    const float* W  = (const float*)d_in[1];
    const float* U  = (const float*)d_in[2];
    const float* bv = (const float*)d_in[3];
    const float* Wd = (const float*)d_in[4];
    const float* bd = (const float*)d_in[5];
    float* out = (float*)d_out;

    hipLaunchKernelGGL(charrnn_rec, dim3(NB), dim3(BLOCK), 0, stream, x, W, U, bv, out);
    hipLaunchKernelGGL(dense_head, dim3(NB * TT / DROWS), dim3(256), 0, stream, out, Wd, bd);
}